// Round 7
// baseline (138.202 us; speedup 1.0000x reference)
//
#include <hip/hip_runtime.h>

// Round-7: occupancy experiment — split each row across a LANE PAIR.
//   h = lane&1: h=0 computes sub-circuits s=0,1; h=1 computes s=2,3.
//   Partial logit-diffs combined with __shfl_xor(d,1); lane h writes
//   out[2*row+h] (fully coalesced 4B/lane).
//   => 524288 threads = 1024 blocks x 512 thr = 4 blocks/CU = 32 waves/CU
//      = 8 waves/SIMD (2x every previous round, which all ran <=4/SIMD).
//   __launch_bounds__(512, 8) caps VGPR at 64; compute working set ~45
//   (x loaded AFTER the register-heavy build phases — rounds 3/6 lesson:
//   xv live across the build is what spilled).
// Work per CU (FMA count, LDS wave-instrs) is conserved; only latency
// exposure changes.  Pre-committed: dur ~67-69 if exposure-bound at
// 4 waves/SIMD; unchanged ~74 if pipe-bound.

__device__ __forceinline__ float layer_angle(const float* __restrict__ w,
                                             int l, int idx) {
    float ang = 0.f;
    #pragma unroll
    for (int g = 0; g < 4; ++g) {
        int cb = (idx >> (3 - g)) & 1;                 // control = wire g
        int tb = (idx >> (3 - ((g + 1) & 3))) & 1;     // target  = wire (g+1)%4
        if (cb) ang += (tb ? 0.5f : -0.5f) * w[l * 4 + g];
    }
    return ang;
}

__global__ __launch_bounds__(512, 8) void fused_qcircuit(
    const float* __restrict__ x,
    const float* __restrict__ weights,
    const float* __restrict__ lin_w,
    const float* __restrict__ lin_b,
    float* __restrict__ out,
    int nrows)
{
    __shared__ float2 U1[256], U2[256], U[256];   // row-major [i*16+j]
    __shared__ float zeta[4][16];
    __shared__ float G[4][256];
    __shared__ float A[4][3][64];
    __shared__ float B[4][9][16];
    __shared__ float C1[4][27][4];
    __shared__ __align__(16) float tabs[4][9][12];  // [s][t0*3+t1][k] pad 12

    int t = threadIdx.x;            // 0..511
    int i = t >> 4, j = t & 15;     // build-phase coords (t<256 only)

    // ---- table build: matmuls on t<256, folds on all 512 ----
    if (t < 256) {
        // U1 = Hhat * D0   (Hhat[i][j] = (-1)^popc(i&j), unnormalized)
        float sgn = (__popc(i & j) & 1) ? -1.f : 1.f;
        float a = layer_angle(weights, 0, j);
        U1[t] = make_float2(sgn * __cosf(a), sgn * __sinf(a));
    }
    // zeta[s][k] = sum_w (lin_w[0,4s+w]-lin_w[1,4s+w]) * (-1)^{bit(3-w) of k}
    if (t < 64) {
        int s = t >> 4, k = t & 15;
        float z = 0.f;
        #pragma unroll
        for (int w = 0; w < 4; ++w) {
            float sg = ((k >> (3 - w)) & 1) ? -1.f : 1.f;
            z += (lin_w[s * 4 + w] - lin_w[16 + s * 4 + w]) * sg;
        }
        zeta[s][k] = z;
    }
    __syncthreads();
    // U2 = Hhat * D1 * U1
    if (t < 256) {
        float ar = 0.f, ai = 0.f;
        for (int k = 0; k < 16; ++k) {
            float sgn = (__popc(i & k) & 1) ? -1.f : 1.f;
            float a = layer_angle(weights, 1, k);
            float cr = sgn * __cosf(a), ci = sgn * __sinf(a);
            float2 u = U1[k * 16 + j];
            ar += cr * u.x - ci * u.y;
            ai += cr * u.y + ci * u.x;
        }
        U2[t] = make_float2(ar, ai);
    }
    __syncthreads();
    // U = Hhat * D2 * U2
    if (t < 256) {
        float ar = 0.f, ai = 0.f;
        for (int k = 0; k < 16; ++k) {
            float sgn = (__popc(i & k) & 1) ? -1.f : 1.f;
            float a = layer_angle(weights, 2, k);
            float cr = sgn * __cosf(a), ci = sgn * __sinf(a);
            float2 u = U2[k * 16 + j];
            ar += cr * u.x - ci * u.y;
            ai += cr * u.y + ci * u.x;
        }
        U[t] = make_float2(ar, ai);
    }
    __syncthreads();
    // G[s][i*16+j] = sum_k zeta[s][k] * Re(conj(U[k,i]) U[k,j])
    if (t < 256) {
        float g[4] = {0, 0, 0, 0};
        for (int k = 0; k < 16; ++k) {
            float2 uki = U[k * 16 + i], ukj = U[k * 16 + j];
            float p = uki.x * ukj.x + uki.y * ukj.y;
            #pragma unroll
            for (int s = 0; s < 4; ++s) g[s] += zeta[s][k] * p;
        }
        #pragma unroll
        for (int s = 0; s < 4; ++s) G[s][t] = g[s];
    }
    __syncthreads();
    // Fold wire3 (LSB): A[s][t3][ih*8+jh]
    for (int e = t; e < 768; e += 512) {
        int m = e / 192, r = e % 192;
        int t3 = r / 64, q = r % 64;
        int ih = q >> 3, jh = q & 7;
        float g00 = G[m][(ih * 2 + 0) * 16 + jh * 2 + 0];
        float g01 = G[m][(ih * 2 + 0) * 16 + jh * 2 + 1];
        float g10 = G[m][(ih * 2 + 1) * 16 + jh * 2 + 0];
        float g11 = G[m][(ih * 2 + 1) * 16 + jh * 2 + 1];
        A[m][t3][q] = (t3 == 0) ? g00 + g11 : (t3 == 1) ? g00 - g11 : g01 + g10;
    }
    __syncthreads();
    // Fold wire2: B[s][t2*3+t3][ih*4+jh]
    for (int e = t; e < 576; e += 512) {
        int m = e / 144, r = e % 144;
        int t2 = r / 48; r %= 48;
        int t3 = r / 16, q = r % 16;
        int ih = q >> 2, jh = q & 3;
        float a00 = A[m][t3][(ih * 2 + 0) * 8 + jh * 2 + 0];
        float a01 = A[m][t3][(ih * 2 + 0) * 8 + jh * 2 + 1];
        float a10 = A[m][t3][(ih * 2 + 1) * 8 + jh * 2 + 0];
        float a11 = A[m][t3][(ih * 2 + 1) * 8 + jh * 2 + 1];
        B[m][t2 * 3 + t3][q] = (t2 == 0) ? a00 + a11
                             : (t2 == 1) ? a00 - a11 : a01 + a10;
    }
    __syncthreads();
    // Fold wire1: C1[s][t1*9+t2*3+t3][ih*2+jh]
    for (int e = t; e < 432; e += 512) {
        int m = e / 108, r = e % 108;
        int t1 = r / 36; r %= 36;
        int t23 = r / 4, q = r % 4;
        int ih = q >> 1, jh = q & 1;
        float b00 = B[m][t23][(ih * 2 + 0) * 4 + jh * 2 + 0];
        float b01 = B[m][t23][(ih * 2 + 0) * 4 + jh * 2 + 1];
        float b10 = B[m][t23][(ih * 2 + 1) * 4 + jh * 2 + 0];
        float b11 = B[m][t23][(ih * 2 + 1) * 4 + jh * 2 + 1];
        C1[m][t1 * 9 + t23][q] = (t1 == 0) ? b00 + b11
                               : (t1 == 1) ? b00 - b11 : b01 + b10;
    }
    __syncthreads();

    // ---- x load: 2 float4 per thread (the half this lane needs).
    //      Issued here so the last fold phase + barrier hide HBM latency;
    //      only 8 VGPRs held across one short phase. ----
    const int h = t & 1;                      // 0: s=0,1   1: s=2,3
    int row = blockIdx.x * 256 + (t >> 1);
    int rc = row < nrows ? row : 0;
    const float4* xp = (const float4*)(x + (size_t)rc * 16);
    float4 va = xp[2 * h], vb = xp[2 * h + 1];

    // Fold wire0 + write padded tiles.  Scale: (1/64)^2 H-norm, (1/2)^4
    // half-angle basis.  lin_b difference folded into tabs[0][0][0]
    // (read only by the h=0 lane of each pair -> counted once per row).
    {
        const float scale = 1.f / 65536.f;
        float bias = lin_b[0] - lin_b[1];
        for (int e = t; e < 324; e += 512) {
            int m = e / 81, r = e % 81;
            int t0 = r / 27, t123 = r % 27;
            const float* c = C1[m][t123];
            float v = (t0 == 0) ? c[0] + c[3] : (t0 == 1) ? c[0] - c[3]
                                              : c[1] + c[2];
            float val = v * scale;
            if (e == 0) val += bias;
            int t1 = t123 / 9, k = t123 % 9;
            tabs[m][t0 * 3 + t1][k] = val;
        }
    }
    __syncthreads();

    // ---- compute: 2 sub-circuits per thread (this lane's half-row) ----
    float d = 0.f;
    #pragma unroll
    for (int k = 0; k < 2; ++k) {
        const int si = h * 2 + k;
        // sub-circuit si wires 0..3 -> angles:
        //   k=0: va.x, va.y, vb.x, vb.y     k=1: va.z, va.w, vb.z, vb.w
        float a0 = k ? va.z : va.x, a1 = k ? va.w : va.y;
        float a2 = k ? vb.z : vb.x, a3 = k ? vb.w : vb.y;
        float C0, S0, C1v, S1, C2, S2, C3, S3;
        __sincosf(a0, &S0, &C0);
        __sincosf(a1, &S1, &C1v);
        __sincosf(a2, &S2, &C2);
        __sincosf(a3, &S3, &C3);
        #pragma unroll
        for (int t0 = 0; t0 < 3; ++t0) {
            float acc = 0.f;
            #pragma unroll
            for (int t1 = 0; t1 < 3; ++t1) {
                const float* tp = &tabs[si][t0 * 3 + t1][0];
                float4 q0 = *(const float4*)tp;        // k0..k3
                float4 q1 = *(const float4*)(tp + 4);  // k4..k7
                float  k8 = tp[8];
                float u0 = fmaf(S3, q0.z, fmaf(C3, q0.y, q0.x));
                float u1 = fmaf(S3, q1.y, fmaf(C3, q1.x, q0.w));
                float u2 = fmaf(S3, k8,   fmaf(C3, q1.w, q1.z));
                float a1v = fmaf(S2, u2, fmaf(C2, u1, u0));
                acc = (t1 == 0) ? acc + a1v
                    : (t1 == 1) ? fmaf(C1v, a1v, acc)
                                : fmaf(S1,  a1v, acc);
            }
            d = (t0 == 0) ? d + acc
              : (t0 == 1) ? fmaf(C0, acc, d)
                          : fmaf(S0, acc, d);
        }
    }

    // combine the lane pair; each lane writes its own output element
    d += __shfl_xor(d, 1);
    if (row < nrows) {
        // h=0: p0 = 1/(1+e^-d);  h=1: 1-p0 = 1/(1+e^d)
        float p = 1.f / (1.f + __expf(h ? d : -d));
        out[(size_t)row * 2 + h] = p;
    }

    // grid-stride fallback (dead when grid covers nrows exactly)
    for (row += gridDim.x * 256; row < nrows; row += gridDim.x * 256) {
        const float4* xq = (const float4*)(x + (size_t)row * 16);
        float4 wa = xq[2 * h], wb = xq[2 * h + 1];
        float dd = 0.f;
        #pragma unroll
        for (int k = 0; k < 2; ++k) {
            const int si = h * 2 + k;
            float a0 = k ? wa.z : wa.x, a1 = k ? wa.w : wa.y;
            float a2 = k ? wb.z : wb.x, a3 = k ? wb.w : wb.y;
            float C0, S0, C1v, S1, C2, S2, C3, S3;
            __sincosf(a0, &S0, &C0);
            __sincosf(a1, &S1, &C1v);
            __sincosf(a2, &S2, &C2);
            __sincosf(a3, &S3, &C3);
            #pragma unroll
            for (int t0 = 0; t0 < 3; ++t0) {
                float acc = 0.f;
                #pragma unroll
                for (int t1 = 0; t1 < 3; ++t1) {
                    const float* tp = &tabs[si][t0 * 3 + t1][0];
                    float4 q0 = *(const float4*)tp;
                    float4 q1 = *(const float4*)(tp + 4);
                    float  k8 = tp[8];
                    float u0 = fmaf(S3, q0.z, fmaf(C3, q0.y, q0.x));
                    float u1 = fmaf(S3, q1.y, fmaf(C3, q1.x, q0.w));
                    float u2 = fmaf(S3, k8,   fmaf(C3, q1.w, q1.z));
                    float a1v = fmaf(S2, u2, fmaf(C2, u1, u0));
                    acc = (t1 == 0) ? acc + a1v
                        : (t1 == 1) ? fmaf(C1v, a1v, acc)
                                    : fmaf(S1,  a1v, acc);
                }
                dd = (t0 == 0) ? dd + acc
                   : (t0 == 1) ? fmaf(C0, acc, dd)
                               : fmaf(S0, acc, dd);
            }
        }
        dd += __shfl_xor(dd, 1);
        float p = 1.f / (1.f + __expf(h ? dd : -dd));
        out[(size_t)row * 2 + h] = p;
    }
}

extern "C" void kernel_launch(void* const* d_in, const int* in_sizes, int n_in,
                              void* d_out, int out_size, void* d_ws, size_t ws_size,
                              hipStream_t stream) {
    const float* x       = (const float*)d_in[0];
    const float* weights = (const float*)d_in[1];
    const float* lin_w   = (const float*)d_in[2];
    const float* lin_b   = (const float*)d_in[3];
    float* out = (float*)d_out;

    int nrows = in_sizes[0] / 16;
    // 256 rows per block (512 threads, 2 threads/row)
    int grid = (nrows + 255) / 256;
    if (grid < 1) grid = 1;
    fused_qcircuit<<<grid, 512, 0, stream>>>(x, weights, lin_w, lin_b, out, nrows);
}

// Round 8
// 87.324 us; speedup vs baseline: 1.5826x; 1.5826x over previous
//
#include <hip/hip_runtime.h>

// Round-8: R7's lane-pair row-split, SINGLE change: __launch_bounds__(512)
// with NO min-waves arg.  R7's (512,8) squeezed the allocator to 32 VGPR ->
// 287MB scratch spill (third spill round: R3/R6 at 128-cap, R7 at 32-cap).
// The compute working set is ~40-50 VGPR, so unconstrained allocation should
// land <=64 naturally -> 4 blocks/CU x 8 waves = 32 waves/CU = 8 waves/SIMD
// with zero spill.  This is the clean occupancy experiment.
//   h = lane&1: h=0 computes sub-circuits s=0,1; h=1 computes s=2,3.
//   d += __shfl_xor(d,1); lane h writes out[2*row+h] (coalesced).

__device__ __forceinline__ float layer_angle(const float* __restrict__ w,
                                             int l, int idx) {
    float ang = 0.f;
    #pragma unroll
    for (int g = 0; g < 4; ++g) {
        int cb = (idx >> (3 - g)) & 1;                 // control = wire g
        int tb = (idx >> (3 - ((g + 1) & 3))) & 1;     // target  = wire (g+1)%4
        if (cb) ang += (tb ? 0.5f : -0.5f) * w[l * 4 + g];
    }
    return ang;
}

__global__ __launch_bounds__(512) void fused_qcircuit(
    const float* __restrict__ x,
    const float* __restrict__ weights,
    const float* __restrict__ lin_w,
    const float* __restrict__ lin_b,
    float* __restrict__ out,
    int nrows)
{
    __shared__ float2 U1[256], U2[256], U[256];   // row-major [i*16+j]
    __shared__ float zeta[4][16];
    __shared__ float G[4][256];
    __shared__ float A[4][3][64];
    __shared__ float B[4][9][16];
    __shared__ float C1[4][27][4];
    __shared__ __align__(16) float tabs[4][9][12];  // [s][t0*3+t1][k] pad 12

    int t = threadIdx.x;            // 0..511
    int i = t >> 4, j = t & 15;     // build-phase coords (t<256 only)

    // ---- table build: matmuls on t<256, folds on all 512 ----
    if (t < 256) {
        // U1 = Hhat * D0   (Hhat[i][j] = (-1)^popc(i&j), unnormalized)
        float sgn = (__popc(i & j) & 1) ? -1.f : 1.f;
        float a = layer_angle(weights, 0, j);
        U1[t] = make_float2(sgn * __cosf(a), sgn * __sinf(a));
    }
    // zeta[s][k] = sum_w (lin_w[0,4s+w]-lin_w[1,4s+w]) * (-1)^{bit(3-w) of k}
    if (t < 64) {
        int s = t >> 4, k = t & 15;
        float z = 0.f;
        #pragma unroll
        for (int w = 0; w < 4; ++w) {
            float sg = ((k >> (3 - w)) & 1) ? -1.f : 1.f;
            z += (lin_w[s * 4 + w] - lin_w[16 + s * 4 + w]) * sg;
        }
        zeta[s][k] = z;
    }
    __syncthreads();
    // U2 = Hhat * D1 * U1
    if (t < 256) {
        float ar = 0.f, ai = 0.f;
        for (int k = 0; k < 16; ++k) {
            float sgn = (__popc(i & k) & 1) ? -1.f : 1.f;
            float a = layer_angle(weights, 1, k);
            float cr = sgn * __cosf(a), ci = sgn * __sinf(a);
            float2 u = U1[k * 16 + j];
            ar += cr * u.x - ci * u.y;
            ai += cr * u.y + ci * u.x;
        }
        U2[t] = make_float2(ar, ai);
    }
    __syncthreads();
    // U = Hhat * D2 * U2
    if (t < 256) {
        float ar = 0.f, ai = 0.f;
        for (int k = 0; k < 16; ++k) {
            float sgn = (__popc(i & k) & 1) ? -1.f : 1.f;
            float a = layer_angle(weights, 2, k);
            float cr = sgn * __cosf(a), ci = sgn * __sinf(a);
            float2 u = U2[k * 16 + j];
            ar += cr * u.x - ci * u.y;
            ai += cr * u.y + ci * u.x;
        }
        U[t] = make_float2(ar, ai);
    }
    __syncthreads();
    // G[s][i*16+j] = sum_k zeta[s][k] * Re(conj(U[k,i]) U[k,j])
    if (t < 256) {
        float g[4] = {0, 0, 0, 0};
        for (int k = 0; k < 16; ++k) {
            float2 uki = U[k * 16 + i], ukj = U[k * 16 + j];
            float p = uki.x * ukj.x + uki.y * ukj.y;
            #pragma unroll
            for (int s = 0; s < 4; ++s) g[s] += zeta[s][k] * p;
        }
        #pragma unroll
        for (int s = 0; s < 4; ++s) G[s][t] = g[s];
    }
    __syncthreads();
    // Fold wire3 (LSB): A[s][t3][ih*8+jh]
    for (int e = t; e < 768; e += 512) {
        int m = e / 192, r = e % 192;
        int t3 = r / 64, q = r % 64;
        int ih = q >> 3, jh = q & 7;
        float g00 = G[m][(ih * 2 + 0) * 16 + jh * 2 + 0];
        float g01 = G[m][(ih * 2 + 0) * 16 + jh * 2 + 1];
        float g10 = G[m][(ih * 2 + 1) * 16 + jh * 2 + 0];
        float g11 = G[m][(ih * 2 + 1) * 16 + jh * 2 + 1];
        A[m][t3][q] = (t3 == 0) ? g00 + g11 : (t3 == 1) ? g00 - g11 : g01 + g10;
    }
    __syncthreads();
    // Fold wire2: B[s][t2*3+t3][ih*4+jh]
    for (int e = t; e < 576; e += 512) {
        int m = e / 144, r = e % 144;
        int t2 = r / 48; r %= 48;
        int t3 = r / 16, q = r % 16;
        int ih = q >> 2, jh = q & 3;
        float a00 = A[m][t3][(ih * 2 + 0) * 8 + jh * 2 + 0];
        float a01 = A[m][t3][(ih * 2 + 0) * 8 + jh * 2 + 1];
        float a10 = A[m][t3][(ih * 2 + 1) * 8 + jh * 2 + 0];
        float a11 = A[m][t3][(ih * 2 + 1) * 8 + jh * 2 + 1];
        B[m][t2 * 3 + t3][q] = (t2 == 0) ? a00 + a11
                             : (t2 == 1) ? a00 - a11 : a01 + a10;
    }
    __syncthreads();
    // Fold wire1: C1[s][t1*9+t2*3+t3][ih*2+jh]
    for (int e = t; e < 432; e += 512) {
        int m = e / 108, r = e % 108;
        int t1 = r / 36; r %= 36;
        int t23 = r / 4, q = r % 4;
        int ih = q >> 1, jh = q & 1;
        float b00 = B[m][t23][(ih * 2 + 0) * 4 + jh * 2 + 0];
        float b01 = B[m][t23][(ih * 2 + 0) * 4 + jh * 2 + 1];
        float b10 = B[m][t23][(ih * 2 + 1) * 4 + jh * 2 + 0];
        float b11 = B[m][t23][(ih * 2 + 1) * 4 + jh * 2 + 1];
        C1[m][t1 * 9 + t23][q] = (t1 == 0) ? b00 + b11
                               : (t1 == 1) ? b00 - b11 : b01 + b10;
    }
    __syncthreads();

    // ---- x load: 2 float4 per thread (the half this lane needs).
    //      Issued here so the last fold phase + barrier hide HBM latency;
    //      only 8 VGPRs held across one short phase. ----
    const int h = t & 1;                      // 0: s=0,1   1: s=2,3
    int row = blockIdx.x * 256 + (t >> 1);
    int rc = row < nrows ? row : 0;
    const float4* xp = (const float4*)(x + (size_t)rc * 16);
    float4 va = xp[2 * h], vb = xp[2 * h + 1];

    // Fold wire0 + write padded tiles.  Scale: (1/64)^2 H-norm, (1/2)^4
    // half-angle basis.  lin_b difference folded into tabs[0][0][0].
    {
        const float scale = 1.f / 65536.f;
        float bias = lin_b[0] - lin_b[1];
        for (int e = t; e < 324; e += 512) {
            int m = e / 81, r = e % 81;
            int t0 = r / 27, t123 = r % 27;
            const float* c = C1[m][t123];
            float v = (t0 == 0) ? c[0] + c[3] : (t0 == 1) ? c[0] - c[3]
                                              : c[1] + c[2];
            float val = v * scale;
            if (e == 0) val += bias;
            int t1 = t123 / 9, k = t123 % 9;
            tabs[m][t0 * 3 + t1][k] = val;
        }
    }
    __syncthreads();

    // ---- compute: 2 sub-circuits per thread (this lane's half-row) ----
    float d = 0.f;
    #pragma unroll
    for (int k = 0; k < 2; ++k) {
        const int si = h * 2 + k;
        // sub-circuit si wires 0..3 -> angles:
        //   k=0: va.x, va.y, vb.x, vb.y     k=1: va.z, va.w, vb.z, vb.w
        float a0 = k ? va.z : va.x, a1 = k ? va.w : va.y;
        float a2 = k ? vb.z : vb.x, a3 = k ? vb.w : vb.y;
        float C0, S0, C1v, S1, C2, S2, C3, S3;
        __sincosf(a0, &S0, &C0);
        __sincosf(a1, &S1, &C1v);
        __sincosf(a2, &S2, &C2);
        __sincosf(a3, &S3, &C3);
        #pragma unroll
        for (int t0 = 0; t0 < 3; ++t0) {
            float acc = 0.f;
            #pragma unroll
            for (int t1 = 0; t1 < 3; ++t1) {
                const float* tp = &tabs[si][t0 * 3 + t1][0];
                float4 q0 = *(const float4*)tp;        // k0..k3
                float4 q1 = *(const float4*)(tp + 4);  // k4..k7
                float  k8 = tp[8];
                float u0 = fmaf(S3, q0.z, fmaf(C3, q0.y, q0.x));
                float u1 = fmaf(S3, q1.y, fmaf(C3, q1.x, q0.w));
                float u2 = fmaf(S3, k8,   fmaf(C3, q1.w, q1.z));
                float a1v = fmaf(S2, u2, fmaf(C2, u1, u0));
                acc = (t1 == 0) ? acc + a1v
                    : (t1 == 1) ? fmaf(C1v, a1v, acc)
                                : fmaf(S1,  a1v, acc);
            }
            d = (t0 == 0) ? d + acc
              : (t0 == 1) ? fmaf(C0, acc, d)
                          : fmaf(S0, acc, d);
        }
    }

    // combine the lane pair; each lane writes its own output element
    d += __shfl_xor(d, 1);
    if (row < nrows) {
        // h=0: p0 = 1/(1+e^-d);  h=1: 1-p0 = 1/(1+e^d)
        float p = 1.f / (1.f + __expf(h ? d : -d));
        out[(size_t)row * 2 + h] = p;
    }

    // grid-stride fallback (dead when grid covers nrows exactly)
    for (row += gridDim.x * 256; row < nrows; row += gridDim.x * 256) {
        const float4* xq = (const float4*)(x + (size_t)row * 16);
        float4 wa = xq[2 * h], wb = xq[2 * h + 1];
        float dd = 0.f;
        #pragma unroll
        for (int k = 0; k < 2; ++k) {
            const int si = h * 2 + k;
            float a0 = k ? wa.z : wa.x, a1 = k ? wa.w : wa.y;
            float a2 = k ? wb.z : wb.x, a3 = k ? wb.w : wb.y;
            float C0, S0, C1v, S1, C2, S2, C3, S3;
            __sincosf(a0, &S0, &C0);
            __sincosf(a1, &S1, &C1v);
            __sincosf(a2, &S2, &C2);
            __sincosf(a3, &S3, &C3);
            #pragma unroll
            for (int t0 = 0; t0 < 3; ++t0) {
                float acc = 0.f;
                #pragma unroll
                for (int t1 = 0; t1 < 3; ++t1) {
                    const float* tp = &tabs[si][t0 * 3 + t1][0];
                    float4 q0 = *(const float4*)tp;
                    float4 q1 = *(const float4*)(tp + 4);
                    float  k8 = tp[8];
                    float u0 = fmaf(S3, q0.z, fmaf(C3, q0.y, q0.x));
                    float u1 = fmaf(S3, q1.y, fmaf(C3, q1.x, q0.w));
                    float u2 = fmaf(S3, k8,   fmaf(C3, q1.w, q1.z));
                    float a1v = fmaf(S2, u2, fmaf(C2, u1, u0));
                    acc = (t1 == 0) ? acc + a1v
                        : (t1 == 1) ? fmaf(C1v, a1v, acc)
                                    : fmaf(S1,  a1v, acc);
                }
                dd = (t0 == 0) ? dd + acc
                   : (t0 == 1) ? fmaf(C0, acc, dd)
                               : fmaf(S0, acc, dd);
            }
        }
        dd += __shfl_xor(dd, 1);
        float p = 1.f / (1.f + __expf(h ? dd : -dd));
        out[(size_t)row * 2 + h] = p;
    }
}

extern "C" void kernel_launch(void* const* d_in, const int* in_sizes, int n_in,
                              void* d_out, int out_size, void* d_ws, size_t ws_size,
                              hipStream_t stream) {
    const float* x       = (const float*)d_in[0];
    const float* weights = (const float*)d_in[1];
    const float* lin_w   = (const float*)d_in[2];
    const float* lin_b   = (const float*)d_in[3];
    float* out = (float*)d_out;

    int nrows = in_sizes[0] / 16;
    // 256 rows per block (512 threads, 2 threads/row)
    int grid = (nrows + 255) / 256;
    if (grid < 1) grid = 1;
    fused_qcircuit<<<grid, 512, 0, stream>>>(x, weights, lin_w, lin_b, out, nrows);
}